// Round 16
// baseline (45.084 us; speedup 1.0000x reference)
//
#include <hip/hip_runtime.h>
#include <math.h>

// MoE router: logits[16384,64] = X[16384,2048] @ W^T, top-2, softmax(2).
// Outputs flat: weights [16384*2] f32, then indices [16384*2] as float.
//
// R13 counted-vmcnt pipeline: 51.4us. R14 fp16 4-product split: 47.6us.
// R15 fused in-block split-K (4 K-slices x 2 token-halves, LDS reduce,
//     top-2 inline): 44.6us.
// R16 K-slice INTERLEAVE: slice s takes chunks d=(ch*4+s)*32 instead of
//     s*512+ch*32. Per iteration the 4 slices' 128B windows become one
//     contiguous 512B span per row, advancing sequentially with ch ->
//     pure streaming X reads (DRAM row-buffer friendly; the old pattern
//     was 128B visits at 2KB stride, ~70% BW). Only the staging source
//     d-offset changes; compute/swizzles/vmcnt/epilogue identical to R15.

#define NTOK 16384
#define DDIM 2048
#define NEXP 64
#define TBLK 64                    // tokens per block
#define KC   32
#define NKG  4                     // K-slices per block
#define NCH  16                    // chunks per slice (512/32)

typedef __attribute__((ext_vector_type(8))) _Float16 f16x8;
typedef __attribute__((ext_vector_type(4))) float f32x4;

// LDS layout (dynamic, 163840 B):
//   XF: 3 bufs x 2048 float4  @ 0       (98304 B)  [buf][kg][64 tok][8 u]
//   WH: 2 bufs x 1024 f16x8   @ 98304   (32768 B)  [buf][kg][64 e][4 u]
//   WM: 2 bufs x 1024 f16x8   @ 131072  (32768 B)
//   red: [4][64][65] f32      @ 0       (66560 B)  aliased onto XF
#define XF_OFF 0
#define WH_OFF 98304
#define WM_OFF 131072

__device__ static inline void gload_lds16(const void* gsrc, void* ldst) {
    __builtin_amdgcn_global_load_lds(
        (const __attribute__((address_space(1))) void*)gsrc,
        (__attribute__((address_space(3))) void*)ldst, 16, 0, 0);
}

// 2-level RNE fp16 split: x = h + m + r, |r| <= 2^-24 |x| (x-(float)h exact)
__device__ static inline void split2h(float x, _Float16& h, _Float16& m) {
    h = (_Float16)x;
    float r = x - (float)h;
    m = (_Float16)r;
}

// ---- prep: split W into fp16 h/m (deterministic, every launch) ----
__global__ __launch_bounds__(256) void wsplit_kernel(
    const float* __restrict__ gw, _Float16* __restrict__ wh,
    _Float16* __restrict__ wm)
{
    for (int i = blockIdx.x * 256 + threadIdx.x; i < NEXP * DDIM;
         i += gridDim.x * 256) {
        _Float16 h, m;
        split2h(gw[i], h, m);
        wh[i] = h; wm[i] = m;
    }
}

// ---- fused: MFMA fp16x4 split-K + LDS reduce + top-2 + softmax ----
__global__ __launch_bounds__(512, 1) void moe_fused_kernel(
    const float* __restrict__ x,      // [NTOK, DDIM] f32
    const _Float16* __restrict__ wh,  // [NEXP, DDIM] fp16
    const _Float16* __restrict__ wm,
    float* __restrict__ out)          // weights then indices
{
    extern __shared__ char smem[];
    float4* XF = (float4*)(smem + XF_OFF);   // unit = 16 B
    f16x8*  WH = (f16x8*)(smem + WH_OFF);
    f16x8*  WM = (f16x8*)(smem + WM_OFF);
    float*  red = (float*)smem;              // [4][64][65], aliased

    const int tid  = threadIdx.x;
    const int lane = tid & 63;
    const int w    = tid >> 6;            // wave 0..7
    const int kg   = w >> 1;              // K-slice 0..3
    const int tq   = w & 1;               // token half 0..1
    const int T0   = blockIdx.x * TBLK;

    // fragment read map: lane l -> row fr, k-group fg (identical to R14/R15)
    const int fr  = lane & 15;
    const int fg  = lane >> 4;
    const int fsw = fg ^ ((fr >> 1) & 3);        // W phys unit key
    const int akey = fr & 7;                     // X swizzle key

    f32x4 acc[2][4];
#pragma unroll
    for (int mi = 0; mi < 2; ++mi)
#pragma unroll
        for (int n = 0; n < 4; ++n) acc[mi][n] = (f32x4){0.f, 0.f, 0.f, 0.f};

    // ---- staging: INTERLEAVED slice mapping. Slice s, chunk ch covers
    //      global d = (ch*NKG + s)*KC -> the 4 slices' windows per chunk are
    //      adjacent (contiguous 512B per row), sequential across chunks.
#define XSTAGE(ch, buf)                                                       \
    {                                                                         \
        _Pragma("unroll")                                                     \
        for (int k = 0; k < 4; ++k) {                                         \
            const int u = tid + k * 512;                                      \
            const int s = u >> 9;                                             \
            const int r = (u >> 3) & 63;                                      \
            const int c = (u & 7) ^ (r & 7);                                  \
            gload_lds16(x + (size_t)(T0 + r) * DDIM + ((ch) * NKG + s) * KC + c * 4, \
                        &XF[(buf) * 2048 + u]);                               \
        }                                                                     \
    }
#define WSTAGE(ch, buf)                                                       \
    {                                                                         \
        _Pragma("unroll")                                                     \
        for (int k = 0; k < 2; ++k) {                                         \
            const int v = tid + k * 512;                                      \
            const int s = v >> 8;                                             \
            const int e = (v >> 2) & 63;                                      \
            const int c = (v & 3) ^ ((e >> 1) & 3);                           \
            const size_t off = (size_t)e * DDIM + ((ch) * NKG + s) * KC + c * 8;\
            gload_lds16(wh + off, &WH[(buf) * 1024 + v]);                     \
            gload_lds16(wm + off, &WM[(buf) * 1024 + v]);                     \
        }                                                                     \
    }
#define WAIT4 asm volatile("s_waitcnt vmcnt(4)" ::: "memory")
#define WAIT0 asm volatile("s_waitcnt vmcnt(0)" ::: "memory")
#define BAR   __builtin_amdgcn_s_barrier()

    // prologue: X0(4), W0(4) = oldest 8, then X1(4) in flight
    XSTAGE(0, 0); WSTAGE(0, 0); XSTAGE(1, 1);
    WAIT4; BAR;

    for (int ch = 0; ch < NCH; ++ch) {
        const int xb = ch % 3;
        const int wb = ch & 1;
        if (ch + 1 < NCH) WSTAGE(ch + 1, (ch + 1) & 1);
        if (ch + 2 < NCH) XSTAGE(ch + 2, (ch + 2) % 3);

        // A fragments: 2-level RNE fp16 split in registers
        const float4* Xc = &XF[xb * 2048 + kg * 512];
        f16x8 ah[2], am[2];
#pragma unroll
        for (int mi = 0; mi < 2; ++mi) {
            const int arow = (tq * 32 + mi * 16 + fr) * 8;
            float4 a0 = Xc[arow + ((fg * 2 + 0) ^ akey)];
            float4 a1 = Xc[arow + ((fg * 2 + 1) ^ akey)];
            float xf8[8] = {a0.x, a0.y, a0.z, a0.w, a1.x, a1.y, a1.z, a1.w};
#pragma unroll
            for (int j = 0; j < 8; ++j) {
                _Float16 hj, mj;
                split2h(xf8[j], hj, mj);
                ah[mi][j] = hj; am[mi][j] = mj;
            }
        }

        const f16x8* WHc = &WH[wb * 1024 + kg * 256];
        const f16x8* WMc = &WM[wb * 1024 + kg * 256];
#pragma unroll
        for (int n = 0; n < 4; ++n) {
            const int bidx = (n * 16 + fr) * 4 + fsw;
            const f16x8 bh = WHc[bidx];
            const f16x8 bm = WMc[bidx];
#pragma unroll
            for (int mi = 0; mi < 2; ++mi) {
                acc[mi][n] = __builtin_amdgcn_mfma_f32_16x16x32_f16(am[mi], bm, acc[mi][n], 0, 0, 0);
                acc[mi][n] = __builtin_amdgcn_mfma_f32_16x16x32_f16(am[mi], bh, acc[mi][n], 0, 0, 0);
                acc[mi][n] = __builtin_amdgcn_mfma_f32_16x16x32_f16(ah[mi], bm, acc[mi][n], 0, 0, 0);
                acc[mi][n] = __builtin_amdgcn_mfma_f32_16x16x32_f16(ah[mi], bh, acc[mi][n], 0, 0, 0);
            }
        }

        if (ch + 2 < NCH)      { WAIT4; BAR; }
        else if (ch + 1 < NCH) { WAIT0; BAR; }
        else                   { BAR; }      // WAR: red aliases XF
    }
#undef XSTAGE
#undef WSTAGE
#undef WAIT4
#undef WAIT0
#undef BAR

    // ---- epilogue 1: C/D frags -> red[kg][exp][tok] (padded 65) ----
    // C/D: col = fr (expert in n-tile), row = fg*4 + j (token) [m89]
#pragma unroll
    for (int mi = 0; mi < 2; ++mi)
#pragma unroll
        for (int n = 0; n < 4; ++n)
#pragma unroll
            for (int j = 0; j < 4; ++j) {
                const int e = n * 16 + fr;
                const int t = tq * 32 + mi * 16 + fg * 4 + j;
                red[kg * 4160 + e * 65 + t] = acc[mi][n][j];
            }
    __syncthreads();

    // ---- epilogue 2: reduce K-slices ascending (owner-only slots) ----
#pragma unroll
    for (int k = 0; k < 8; ++k) {
        const int q = tid + k * 512;
        const int e = q >> 6;
        const int t = q & 63;
        float s = red[0 * 4160 + e * 65 + t];
#pragma unroll
        for (int sl = 1; sl < NKG; ++sl)
            s += red[sl * 4160 + e * 65 + t];
        red[e * 65 + t] = s;
    }
    __syncthreads();

    // ---- epilogue 3: top-2 + softmax (lane t scans [e][t], conflict-free)
    if (tid < TBLK) {
        const int t = tid;
        float m1 = -INFINITY, m2 = -INFINITY;
        int i1 = 0, i2 = 0;
        for (int e = 0; e < NEXP; ++e) {
            float v = red[e * 65 + t];
            if (v > m1) {              // strict '>' = lowest index on ties
                m2 = m1; i2 = i1;
                m1 = v;  i1 = e;
            } else if (v > m2) {
                m2 = v;  i2 = e;
            }
        }
        float e2 = expf(m2 - m1);
        float denom = 1.f + e2;
        const int gt = T0 + t;
        out[gt * 2 + 0] = 1.f / denom;
        out[gt * 2 + 1] = e2 / denom;
        out[NTOK * 2 + gt * 2 + 0] = (float)i1;
        out[NTOK * 2 + gt * 2 + 1] = (float)i2;
    }
}

extern "C" void kernel_launch(void* const* d_in, const int* in_sizes, int n_in,
                              void* d_out, int out_size, void* d_ws, size_t ws_size,
                              hipStream_t stream) {
    const float* x  = (const float*)d_in[0];   // [4,4096,2048] f32
    const float* gw = (const float*)d_in[1];   // [64,2048] f32
    float* out = (float*)d_out;

    // ws layout: Wh|Wm (2 x 256KB fp16)
    _Float16* wh = (_Float16*)d_ws;
    _Float16* wm = wh + NEXP * DDIM;

    wsplit_kernel<<<dim3(256), dim3(256), 0, stream>>>(gw, wh, wm);
    moe_fused_kernel<<<dim3(NTOK / TBLK), dim3(512), 163840, stream>>>(
        x, wh, wm, out);
}

// Round 17
// 41.083 us; speedup vs baseline: 1.0974x; 1.0974x over previous
//
#include <hip/hip_runtime.h>
#include <math.h>

// MoE router: logits[16384,64] = X[16384,2048] @ W^T, top-2, softmax(2).
// Outputs flat: weights [16384*2] f32, then indices [16384*2] as float.
//
// R14 fp16 4-product (2-level RNE split, Sterbenz-exact residual): 47.6us.
// R15 fused in-block split-K + LDS reduce + inline top-2: 44.6us.
// R16 K-slice interleave: NEUTRAL (DRAM-pattern theory wrong; reverted to
//     whichever mapping -- kept interleaved, it's equivalent).
// R17 SINGLE KERNEL: W staged as raw f32 (same bytes as Wh+Wm f16) and
//     split to fp16 h/m in registers after the fragment read, same as X.
//     Deletes the wsplit kernel + its dispatch gap + 1MB W HBM round-trip.
//     W frag reads: 8 ds_read_b128/wave/chunk (same count as before), X-style
//     8-unit XOR swizzle key e&7 = fr&7 (A/B logical-k symmetry, R8/R9-
//     verified). vmcnt re-derived: X4+W4 = 8 DMA/thr/iter, outstanding 12,
//     certify oldest 8 -> vmcnt(4) (unchanged). LDS 96K X + 64K W = 160KB.

#define NTOK 16384
#define DDIM 2048
#define NEXP 64
#define TBLK 64                    // tokens per block
#define KC   32
#define NKG  4                     // K-slices per block
#define NCH  16                    // chunks per slice

typedef __attribute__((ext_vector_type(8))) _Float16 f16x8;
typedef __attribute__((ext_vector_type(4))) float f32x4;

// LDS layout (dynamic, 163840 B):
//   XF: 3 bufs x 2048 float4 @ 0      (98304 B) [buf][kg][64 tok][8 u]
//   WF: 2 bufs x 2048 float4 @ 98304  (65536 B) [buf][kg][64 e][8 u]
//   red: [4][64][65] f32     @ 0      (66560 B) aliased onto XF
#define XF_OFF 0
#define WF_OFF 98304

__device__ static inline void gload_lds16(const void* gsrc, void* ldst) {
    __builtin_amdgcn_global_load_lds(
        (const __attribute__((address_space(1))) void*)gsrc,
        (__attribute__((address_space(3))) void*)ldst, 16, 0, 0);
}

// 2-level RNE fp16 split: x = h + m + r, |r| <= 2^-24 |x| (x-(float)h exact)
__device__ static inline void split2h(float x, _Float16& h, _Float16& m) {
    h = (_Float16)x;
    float r = x - (float)h;
    m = (_Float16)r;
}

// ---- fused: stage X,W f32 -> split in regs -> MFMA fp16x4 -> reduce -> top2
__global__ __launch_bounds__(512, 1) void moe_fused_kernel(
    const float* __restrict__ x,      // [NTOK, DDIM] f32
    const float* __restrict__ gw,     // [NEXP, DDIM] f32
    float* __restrict__ out)          // weights then indices
{
    extern __shared__ char smem[];
    float4* XF = (float4*)(smem + XF_OFF);   // unit = 16 B
    float4* WF = (float4*)(smem + WF_OFF);
    float*  red = (float*)smem;              // [4][64][65], aliased

    const int tid  = threadIdx.x;
    const int lane = tid & 63;
    const int w    = tid >> 6;            // wave 0..7
    const int kg   = w >> 1;              // K-slice 0..3
    const int tq   = w & 1;               // token half 0..1
    const int T0   = blockIdx.x * TBLK;

    // fragment read map: lane l -> row fr, k-group fg
    const int fr  = lane & 15;
    const int fg  = lane >> 4;
    const int akey = fr & 7;              // XOR swizzle key (rows: tok or e)

    f32x4 acc[2][4];
#pragma unroll
    for (int mi = 0; mi < 2; ++mi)
#pragma unroll
        for (int n = 0; n < 4; ++n) acc[mi][n] = (f32x4){0.f, 0.f, 0.f, 0.f};

    // ---- staging: interleaved slice mapping, d = (ch*NKG + s)*KC.
    //      X: 2048 units (4/thr). W: 2048 units (4/thr). Same swizzle form.
#define XSTAGE(ch, buf)                                                       \
    {                                                                         \
        _Pragma("unroll")                                                     \
        for (int k = 0; k < 4; ++k) {                                         \
            const int u = tid + k * 512;                                      \
            const int s = u >> 9;                                             \
            const int r = (u >> 3) & 63;                                      \
            const int c = (u & 7) ^ (r & 7);                                  \
            gload_lds16(x + (size_t)(T0 + r) * DDIM + ((ch) * NKG + s) * KC + c * 4, \
                        &XF[(buf) * 2048 + u]);                               \
        }                                                                     \
    }
#define WSTAGE(ch, buf)                                                       \
    {                                                                         \
        _Pragma("unroll")                                                     \
        for (int k = 0; k < 4; ++k) {                                         \
            const int u = tid + k * 512;                                      \
            const int s = u >> 9;                                             \
            const int e = (u >> 3) & 63;                                      \
            const int c = (u & 7) ^ (e & 7);                                  \
            gload_lds16(gw + (size_t)e * DDIM + ((ch) * NKG + s) * KC + c * 4,\
                        &WF[(buf) * 2048 + u]);                               \
        }                                                                     \
    }
#define WAIT4 asm volatile("s_waitcnt vmcnt(4)" ::: "memory")
#define WAIT0 asm volatile("s_waitcnt vmcnt(0)" ::: "memory")
#define BAR   __builtin_amdgcn_s_barrier()

    // prologue: X0(4), W0(4) = oldest 8, then X1(4) in flight
    XSTAGE(0, 0); WSTAGE(0, 0); XSTAGE(1, 1);
    WAIT4; BAR;

    for (int ch = 0; ch < NCH; ++ch) {
        const int xb = ch % 3;
        const int wb = ch & 1;
        if (ch + 1 < NCH) WSTAGE(ch + 1, (ch + 1) & 1);
        if (ch + 2 < NCH) XSTAGE(ch + 2, (ch + 2) % 3);

        // A fragments: 2-level RNE fp16 split in registers
        const float4* Xc = &XF[xb * 2048 + kg * 512];
        f16x8 ah[2], am[2];
#pragma unroll
        for (int mi = 0; mi < 2; ++mi) {
            const int arow = (tq * 32 + mi * 16 + fr) * 8;
            float4 a0 = Xc[arow + ((fg * 2 + 0) ^ akey)];
            float4 a1 = Xc[arow + ((fg * 2 + 1) ^ akey)];
            float xf8[8] = {a0.x, a0.y, a0.z, a0.w, a1.x, a1.y, a1.z, a1.w};
#pragma unroll
            for (int j = 0; j < 8; ++j) {
                _Float16 hj, mj;
                split2h(xf8[j], hj, mj);
                ah[mi][j] = hj; am[mi][j] = mj;
            }
        }

        // B fragments: read f32 pairs, split in registers (key e&7 == fr&7)
        const float4* Wc = &WF[wb * 2048 + kg * 512];
#pragma unroll
        for (int n = 0; n < 4; ++n) {
            const int brow = (n * 16 + fr) * 8;
            float4 b0 = Wc[brow + ((fg * 2 + 0) ^ akey)];
            float4 b1 = Wc[brow + ((fg * 2 + 1) ^ akey)];
            float wf8[8] = {b0.x, b0.y, b0.z, b0.w, b1.x, b1.y, b1.z, b1.w};
            f16x8 bh, bm;
#pragma unroll
            for (int j = 0; j < 8; ++j) {
                _Float16 hj, mj;
                split2h(wf8[j], hj, mj);
                bh[j] = hj; bm[j] = mj;
            }
#pragma unroll
            for (int mi = 0; mi < 2; ++mi) {
                acc[mi][n] = __builtin_amdgcn_mfma_f32_16x16x32_f16(am[mi], bm, acc[mi][n], 0, 0, 0);
                acc[mi][n] = __builtin_amdgcn_mfma_f32_16x16x32_f16(am[mi], bh, acc[mi][n], 0, 0, 0);
                acc[mi][n] = __builtin_amdgcn_mfma_f32_16x16x32_f16(ah[mi], bm, acc[mi][n], 0, 0, 0);
                acc[mi][n] = __builtin_amdgcn_mfma_f32_16x16x32_f16(ah[mi], bh, acc[mi][n], 0, 0, 0);
            }
        }

        if (ch + 2 < NCH)      { WAIT4; BAR; }
        else if (ch + 1 < NCH) { WAIT0; BAR; }
        else                   { BAR; }      // WAR: red aliases XF
    }
#undef XSTAGE
#undef WSTAGE
#undef WAIT4
#undef WAIT0
#undef BAR

    // ---- epilogue 1: C/D frags -> red[kg][exp][tok] (padded 65) ----
    // C/D: col = fr (expert in n-tile), row = fg*4 + j (token) [m89]
#pragma unroll
    for (int mi = 0; mi < 2; ++mi)
#pragma unroll
        for (int n = 0; n < 4; ++n)
#pragma unroll
            for (int j = 0; j < 4; ++j) {
                const int e = n * 16 + fr;
                const int t = tq * 32 + mi * 16 + fg * 4 + j;
                red[kg * 4160 + e * 65 + t] = acc[mi][n][j];
            }
    __syncthreads();

    // ---- epilogue 2: reduce K-slices ascending (owner-only slots) ----
#pragma unroll
    for (int k = 0; k < 8; ++k) {
        const int q = tid + k * 512;
        const int e = q >> 6;
        const int t = q & 63;
        float s = red[0 * 4160 + e * 65 + t];
#pragma unroll
        for (int sl = 1; sl < NKG; ++sl)
            s += red[sl * 4160 + e * 65 + t];
        red[e * 65 + t] = s;
    }
    __syncthreads();

    // ---- epilogue 3: top-2 + softmax (lane t scans [e][t], conflict-free)
    if (tid < TBLK) {
        const int t = tid;
        float m1 = -INFINITY, m2 = -INFINITY;
        int i1 = 0, i2 = 0;
        for (int e = 0; e < NEXP; ++e) {
            float v = red[e * 65 + t];
            if (v > m1) {              // strict '>' = lowest index on ties
                m2 = m1; i2 = i1;
                m1 = v;  i1 = e;
            } else if (v > m2) {
                m2 = v;  i2 = e;
            }
        }
        float e2 = expf(m2 - m1);
        float denom = 1.f + e2;
        const int gt = T0 + t;
        out[gt * 2 + 0] = 1.f / denom;
        out[gt * 2 + 1] = e2 / denom;
        out[NTOK * 2 + gt * 2 + 0] = (float)i1;
        out[NTOK * 2 + gt * 2 + 1] = (float)i2;
    }
}

extern "C" void kernel_launch(void* const* d_in, const int* in_sizes, int n_in,
                              void* d_out, int out_size, void* d_ws, size_t ws_size,
                              hipStream_t stream) {
    const float* x  = (const float*)d_in[0];   // [4,4096,2048] f32
    const float* gw = (const float*)d_in[1];   // [64,2048] f32
    float* out = (float*)d_out;
    (void)d_ws; (void)ws_size;

    moe_fused_kernel<<<dim3(NTOK / TBLK), dim3(512), 163840, stream>>>(
        x, gw, out);
}